// Round 16
// baseline (608.590 us; speedup 1.0000x reference)
//
#include <hip/hip_runtime.h>
#include <math.h>

#define TLEN 2048
#define TP 256

typedef double d4 __attribute__((ext_vector_type(4)));

// ---------------- helpers ----------------
__device__ __forceinline__ double block_reduce_sum_d(double v, double* sm) {
#pragma unroll
  for (int off = 32; off > 0; off >>= 1) v += __shfl_down(v, off, 64);
  int lane = threadIdx.x & 63, wid = threadIdx.x >> 6;
  __syncthreads();
  if (lane == 0) sm[wid] = v;
  __syncthreads();
  double r = sm[0] + sm[1] + sm[2] + sm[3];
  __syncthreads();
  return r;
}

// ---------------- f64-MFMA layout probe (wave-parallel, proven round 8) -------------
// tbl: ma[64] ka[64] kb[64] nb[64] rd[64*4] cd[64*4] ok   (769 ints)
__global__ void k_probe_f64(int* __restrict__ tbl) {
  int l = threadIdx.x;  // single wave of 64
  __shared__ int kaS[64], kbS[64];
  __shared__ int cnt[256];
  int rdv[4] = {-1, -1, -1, -1}, cdv[4] = {-1, -1, -1, -1};
  int mav = -1, nbv = -1;
  int okr = 1;
  int nrow = 0, ncol = 0;
  kaS[l] = -1; kbS[l] = -1;
  __syncthreads();

  for (int j = 0; j < 64; ++j) {
    double a = (l == j) ? 1.0 : 0.0;
    d4 acc = {0.0, 0.0, 0.0, 0.0};
    acc = __builtin_amdgcn_mfma_f64_16x16x4f64(a, 1.0, acc, 0, 0, 0);
    int mylab = -1;
#pragma unroll
    for (int v = 0; v < 4; ++v) if (acc[v] != 0.0 && rdv[v] >= 0) mylab = rdv[v];
#pragma unroll
    for (int off = 32; off >= 1; off >>= 1) {
      int o = __shfl_xor(mylab, off);
      mylab = mylab > o ? mylab : o;
    }
    int label = (mylab < 0) ? nrow : mylab;
    if (mylab < 0) nrow++;
    if (label >= 16) okr = 0;
#pragma unroll
    for (int v = 0; v < 4; ++v) if (acc[v] != 0.0) rdv[v] = label;
    if (l == j) mav = label;
  }

  for (int j = 0; j < 64; ++j) {
    double bb = (l == j) ? 1.0 : 0.0;
    d4 acc = {0.0, 0.0, 0.0, 0.0};
    acc = __builtin_amdgcn_mfma_f64_16x16x4f64(1.0, bb, acc, 0, 0, 0);
    int mylab = -1;
#pragma unroll
    for (int v = 0; v < 4; ++v) if (acc[v] != 0.0 && cdv[v] >= 0) mylab = cdv[v];
#pragma unroll
    for (int off = 32; off >= 1; off >>= 1) {
      int o = __shfl_xor(mylab, off);
      mylab = mylab > o ? mylab : o;
    }
    int label = (mylab < 0) ? ncol : mylab;
    if (mylab < 0) ncol++;
    if (label >= 16) okr = 0;
#pragma unroll
    for (int v = 0; v < 4; ++v) if (acc[v] != 0.0) cdv[v] = label;
    if (l == j) nbv = label;
  }

  unsigned long long row0 = __ballot(mav == 0);
  if (__popcll(row0) != 4) okr = 0;
  for (int i = 0; i < 4; ++i) {
    int rep = -1, idx = -1;
    for (int t = 0; t < 64; ++t)
      if ((row0 >> t) & 1ull) { if (++idx == i) { rep = t; break; } }
    double a = (l == rep) ? 1.0 : 0.0;
    double bb = (double)(l + 1);
    d4 acc = {0.0, 0.0, 0.0, 0.0};
    acc = __builtin_amdgcn_mfma_f64_16x16x4f64(a, bb, acc, 0, 0, 0);
#pragma unroll
    for (int v = 0; v < 4; ++v)
      if (rdv[v] == 0) {
        int jp = (int)(acc[v] + 0.5) - 1;
        if (jp >= 0 && jp < 64) kbS[jp] = i; else okr = 0;
      }
  }
  __syncthreads();
  int kbv = kbS[l];

  for (int i = 0; i < 4; ++i) {
    unsigned long long bm = __ballot(kbv == i);
    int rep = -1;
    if (bm != 0ull) { rep = 0; while (!((bm >> rep) & 1ull)) ++rep; }
    else okr = 0;
    int nc = (rep >= 0) ? __shfl(nbv, rep) : -2;
    double bb = (l == rep) ? 1.0 : 0.0;
    double aa = (double)(l + 1);
    d4 acc = {0.0, 0.0, 0.0, 0.0};
    acc = __builtin_amdgcn_mfma_f64_16x16x4f64(aa, bb, acc, 0, 0, 0);
#pragma unroll
    for (int v = 0; v < 4; ++v)
      if (cdv[v] == nc) {
        int jp = (int)(acc[v] + 0.5) - 1;
        if (jp >= 0 && jp < 64) kaS[jp] = i; else okr = 0;
      }
  }
  __syncthreads();
  int kav = kaS[l];

  if (nrow != 16 || ncol != 16) okr = 0;
  if (mav < 0 || mav > 15 || nbv < 0 || nbv > 15 ||
      kav < 0 || kav > 3 || kbv < 0 || kbv > 3) okr = 0;
#pragma unroll
  for (int v = 0; v < 4; ++v)
    if (rdv[v] < 0 || rdv[v] > 15 || cdv[v] < 0 || cdv[v] > 15) okr = 0;
  cnt[l] = 0; cnt[64 + l] = 0; cnt[128 + l] = 0; cnt[192 + l] = 0;
  __syncthreads();
  if (mav >= 0 && mav < 16 && kav >= 0 && kav < 4) atomicAdd(&cnt[mav * 4 + kav], 1);
  if (kbv >= 0 && kbv < 4 && nbv >= 0 && nbv < 16) atomicAdd(&cnt[64 + kbv * 16 + nbv], 1);
  __syncthreads();
  if (cnt[l] != 1 || cnt[64 + l] != 1) okr = 0;
  __syncthreads();
  cnt[l] = 0; cnt[64 + l] = 0; cnt[128 + l] = 0; cnt[192 + l] = 0;
  __syncthreads();
#pragma unroll
  for (int v = 0; v < 4; ++v)
    if (rdv[v] >= 0 && rdv[v] < 16 && cdv[v] >= 0 && cdv[v] < 16)
      atomicAdd(&cnt[rdv[v] * 16 + cdv[v]], 1);
  __syncthreads();
#pragma unroll
  for (int v = 0; v < 4; ++v) if (cnt[l * 4 + v] != 1) okr = 0;
  if (mav == 0) {
    int rank = (int)__popcll(row0 & ((1ull << l) - 1ull));
    if (kav != rank) okr = 0;
  }
  unsigned long long good = __ballot(okr != 0);
  tbl[l] = mav; tbl[64 + l] = kav; tbl[128 + l] = kbv; tbl[192 + l] = nbv;
#pragma unroll
  for (int v = 0; v < 4; ++v) {
    tbl[256 + l * 4 + v] = rdv[v];
    tbl[512 + l * 4 + v] = cdv[v];
  }
  if (l == 0) tbl[768] = (good == 0xFFFFFFFFFFFFFFFFull) ? 1 : 0;
}

// ---------------- repack tconv1 weights: w[o][i][k] -> wT[k][i][o] (f32, exact) ------
__global__ void k_repack_w(const float* __restrict__ w, float* __restrict__ wT) {
  int idx = blockIdx.x * 256 + threadIdx.x;
  if (idx >= 64 * 64 * 15) return;
  int o = idx & 63, i = (idx >> 6) & 63, k = idx >> 12;
  wT[idx] = w[(o * 64 + i) * 15 + k];
}

// ---------------- transpose weights to f64 [i][o] layouts (exact conversions) -------
__global__ void k_prep_w64(const float* __restrict__ w1, const float* __restrict__ w2,
                           const float* __restrict__ w4, double* __restrict__ w1T,
                           double* __restrict__ w2T, double* __restrict__ w4T) {
  int idx = blockIdx.x * 256 + threadIdx.x;
  if (idx < 98304) {                       // w1: 128 o x 768 i -> [i][128]
    int i = idx >> 7, o = idx & 127;
    w1T[idx] = (double)w1[(size_t)o * 768 + i];
  } else if (idx < 106496) {               // w2: 64 o x 128 i -> [i][64]
    int r = idx - 98304;
    int i = r >> 6, o = r & 63;
    w2T[r] = (double)w2[(size_t)o * 128 + i];
  } else if (idx < 110592) {               // w4: 64 o x 64 i -> [i][64]
    int r = idx - 106496;
    int i = r >> 6, o = r & 63;
    w4T[r] = (double)w4[(size_t)o * 64 + i];
  }
}

// ---------------- pooled streams -> row-major [row][tp] ----------------
template <typename T>
__global__ __launch_bounds__(256) void k_pool_ct(const float* __restrict__ xb,
                                                 T* __restrict__ curvp,
                                                 T* __restrict__ tangp) {
  int row = blockIdx.x;  // b*64+c
  int b = row >> 6, c = row & 63;
  int tid = threadIdx.x;
  const float* s1 = xb + ((size_t)((b * 3 + 1) * 64 + c)) * TLEN + tid * 8;
  const float* s2 = xb + ((size_t)((b * 3 + 2) * 64 + c)) * TLEN + tid * 8;
  double p1 = 0.0, p2 = 0.0;
#pragma unroll
  for (int j = 0; j < 8; ++j) { p1 += (double)s1[j]; p2 += (double)s2[j]; }
  curvp[(size_t)row * TP + tid] = (T)(p1 * 0.125);
  tangp[(size_t)row * TP + tid] = (T)(p2 * 0.125);
}

// ---------------- instance-norm stats only: per-row scale/shift ---------------------
template <typename T>
__global__ __launch_bounds__(256) void k_stats(const T* __restrict__ h,
                                               const float* __restrict__ gw,
                                               const float* __restrict__ gb,
                                               int chmask,
                                               double* __restrict__ sc,
                                               double* __restrict__ sh) {
  __shared__ double sm[4];
  int row = blockIdx.x, tid = threadIdx.x;
  int ch = row & chmask;
  const T* base = h + (size_t)row * TLEN + tid * 8;
  double v[8];
#pragma unroll
  for (int j = 0; j < 8; ++j) v[j] = (double)base[j];
  double s = 0.0;
#pragma unroll
  for (int j = 0; j < 8; ++j) s += v[j];
  double mean = block_reduce_sum_d(s, sm) * (1.0 / 2048.0);
  double sq = 0.0;
#pragma unroll
  for (int j = 0; j < 8; ++j) { double d = v[j] - mean; sq += d * d; }
  double var = block_reduce_sum_d(sq, sm) * (1.0 / 2048.0);
  double scale = (double)gw[ch] / sqrt(var + 1e-5);
  double shift = (double)gb[ch] - mean * scale;
  if (tid == 0) { sc[row] = scale; sh[row] = shift; }
}

// ---------------- enc+conv1 via f64 MFMA: A from global f64 [i][o], dbuf B ----------
// 128 o x 64 t tile, 4 waves (wave wv: o0=wv*32). LDS = Bs[2] (34.8 KB, dbuf ->
// ONE barrier per k-chunk). A loads coalesced (4 rows x 16 consecutive f64).
// Same values & accumulation order as rounds 8-15 -> bit-identical h1.
template <typename T>
__global__ __launch_bounds__(256, 4) void k_enc1_mfma(const float* __restrict__ xb,
                                                      const double* __restrict__ w1T,
                                                      const float* __restrict__ mu,
                                                      const float* __restrict__ sigma,
                                                      T* __restrict__ h1,
                                                      const int* __restrict__ tbl) {
  if (tbl[768] == 0) return;   // probe failed -> VALU twin handles it
  __shared__ double Bs[2][32][68];
  int b = blockIdx.x, t0 = blockIdx.y * 64, tid = threadIdx.x;
  int wv = tid >> 6, l = tid & 63;
  int o0 = wv * 32;
  int t_ma = tbl[l], t_ka = tbl[64 + l], t_kb = tbl[128 + l], t_nb = tbl[192 + l];
  int t_rd[4], t_cd[4];
#pragma unroll
  for (int v = 0; v < 4; ++v) { t_rd[v] = tbl[256 + l * 4 + v]; t_cd[v] = tbl[512 + l * 4 + v]; }
  double smu[4], sinv[4];
#pragma unroll
  for (int g = 0; g < 4; ++g) {
    smu[g] = (double)mu[g];
    double s = (double)sigma[g];
    sinv[g] = 1.0 / (2.0 * s * s + 1e-6);
  }
  d4 acc[2][4];
#pragma unroll
  for (int r = 0; r < 2; ++r)
#pragma unroll
    for (int c = 0; c < 4; ++c) acc[r][c] = (d4){0.0, 0.0, 0.0, 0.0};

  int sc_ = tid >> 5, sl2 = tid & 31;   // staging: c-row 0..7, t-lane 0..31
  int st = 2 * sl2;

  // prologue: exp-encode chunk 0
  double e[8];
  {
    float2 x2 = *(const float2*)(xb + ((size_t)((b * 3 + 0) * 64 + 0 + sc_)) * TLEN + t0 + st);
    double xv0 = (double)x2.x, xv1 = (double)x2.y;
#pragma unroll
    for (int g = 0; g < 4; ++g) {
      double d0 = xv0 - smu[g], d1 = xv1 - smu[g];
      e[2 * g] = exp(-d0 * d0 * sinv[g]);
      e[2 * g + 1] = exp(-d1 * d1 * sinv[g]);
    }
  }

  for (int kc = 0; kc < 24; ++kc) {
    int cur = kc & 1;
    int i0 = kc * 32;
#pragma unroll
    for (int g = 0; g < 4; ++g) {
      double2 ev = {e[2 * g], e[2 * g + 1]};
      *(double2*)&Bs[cur][sc_ * 4 + g][st] = ev;
    }
    __syncthreads();   // Bs[cur] ready; prior reads of Bs[cur] finished before barrier kc-1
    // prefetch next chunk's x (load issued before MFMA burst)
    float2 x2n = {0.0f, 0.0f};
    if (kc < 23) {
      int i0n = i0 + 32;
      int f = i0n >> 8, cb = (i0n >> 2) & 63;
      x2n = *(const float2*)(xb + ((size_t)((b * 3 + f) * 64 + cb + sc_)) * TLEN + t0 + st);
    }
    // MFMA burst: A direct from global f64 (L2), B from LDS
#pragma unroll
    for (int k4 = 0; k4 < 32; k4 += 4) {
      const double* wrow = w1T + (size_t)(i0 + k4 + t_ka) * 128;
      double aF0 = wrow[o0 + t_ma];
      double aF1 = wrow[o0 + 16 + t_ma];
      double bF[4];
#pragma unroll
      for (int c = 0; c < 4; ++c) bF[c] = Bs[cur][k4 + t_kb][c * 16 + t_nb];
#pragma unroll
      for (int c = 0; c < 4; ++c) {
        acc[0][c] = __builtin_amdgcn_mfma_f64_16x16x4f64(aF0, bF[c], acc[0][c], 0, 0, 0);
        acc[1][c] = __builtin_amdgcn_mfma_f64_16x16x4f64(aF1, bF[c], acc[1][c], 0, 0, 0);
      }
    }
    // exp-encode next chunk (VALU work overlapped with MFMA drain)
    if (kc < 23) {
      double xv0 = (double)x2n.x, xv1 = (double)x2n.y;
#pragma unroll
      for (int g = 0; g < 4; ++g) {
        double d0 = xv0 - smu[g], d1 = xv1 - smu[g];
        e[2 * g] = exp(-d0 * d0 * sinv[g]);
        e[2 * g + 1] = exp(-d1 * d1 * sinv[g]);
      }
    }
  }
#pragma unroll
  for (int r = 0; r < 2; ++r)
#pragma unroll
    for (int c = 0; c < 4; ++c)
#pragma unroll
      for (int v = 0; v < 4; ++v) {
        int o = o0 + r * 16 + t_rd[v];
        h1[((size_t)(b * 128 + o)) * TLEN + t0 + c * 16 + t_cd[v]] = (T)acc[r][c][v];
      }
}

// ---------------- enc+conv1 VALU twin (runs only if probe failed) -------------------
template <typename T>
__global__ __launch_bounds__(256, 4) void k_enc1_valu(const float* __restrict__ xb,
                                                      const float* __restrict__ w,
                                                      const float* __restrict__ mu,
                                                      const float* __restrict__ sigma,
                                                      T* __restrict__ h1,
                                                      const int* __restrict__ tbl) {
  if (tbl[768] != 0) return;
  __shared__ float AsT[32][132];
  __shared__ double Bs[32][64];
  __shared__ double smu[4], sinv[4];
  int b = blockIdx.x, t0 = blockIdx.y * 64, tid = threadIdx.x;
  if (tid < 4) {
    smu[tid] = (double)mu[tid];
    double s = (double)sigma[tid];
    sinv[tid] = 1.0 / (2.0 * s * s + 1e-6);
  }
  double acc[8][4] = {};
  int to = (tid >> 4) * 8, l = tid & 15;
  for (int kc = 0; kc < 24; ++kc) {
    int i0 = kc * 32;
    __syncthreads();
    {
      int idx = tid * 4;
#pragma unroll
      for (int rep = 0; rep < 4; ++rep) {
        int o = idx >> 5, ii = idx & 31;
        float4 v4 = *(const float4*)(w + (size_t)o * 768 + i0 + ii);
        AsT[ii][o] = v4.x; AsT[ii + 1][o] = v4.y; AsT[ii + 2][o] = v4.z; AsT[ii + 3][o] = v4.w;
        idx += 1024;
      }
    }
    {
      int f = i0 >> 8;
      int cb = (i0 >> 2) & 63;
      int c = tid >> 5, l2 = tid & 31;
      int t = 2 * l2;
      float2 x2 = *(const float2*)(xb + ((size_t)((b * 3 + f) * 64 + cb + c)) * TLEN + t0 + t);
      double xv0 = (double)x2.x, xv1 = (double)x2.y;
#pragma unroll
      for (int g = 0; g < 4; ++g) {
        double m = smu[g], inv = sinv[g];
        double d0 = xv0 - m, d1 = xv1 - m;
        double2 e = {exp(-d0 * d0 * inv), exp(-d1 * d1 * inv)};
        *(double2*)&Bs[c * 4 + g][t] = e;
      }
    }
    __syncthreads();
#pragma unroll
    for (int kk = 0; kk < 32; ++kk) {
      float4 a0 = *(const float4*)&AsT[kk][to];
      float4 a1 = *(const float4*)&AsT[kk][to + 4];
      double a[8] = {(double)a0.x, (double)a0.y, (double)a0.z, (double)a0.w,
                     (double)a1.x, (double)a1.y, (double)a1.z, (double)a1.w};
      double bb[4];
#pragma unroll
      for (int j = 0; j < 2; ++j) {
        double2 p = *(const double2*)&Bs[kk][2 * l + 32 * j];
        bb[2 * j] = p.x; bb[2 * j + 1] = p.y;
      }
#pragma unroll
      for (int q = 0; q < 8; ++q)
#pragma unroll
        for (int j = 0; j < 4; ++j) acc[q][j] += a[q] * bb[j];
    }
  }
#pragma unroll
  for (int q = 0; q < 8; ++q) {
    T* op = h1 + ((size_t)(b * 128 + to + q)) * TLEN + t0;
    op[2 * l]      = (T)acc[q][0];
    op[2 * l + 1]  = (T)acc[q][1];
    op[2 * l + 32] = (T)acc[q][2];
    op[2 * l + 33] = (T)acc[q][3];
  }
}

// ---------------- 1x1 conv via f64 MFMA: A global f64 [i][o], dbuf B, fused norm ----
template <int K, typename T>
__global__ __launch_bounds__(256, 4) void k_conv1x1_mfma(const T* __restrict__ in,
                                                         const double* __restrict__ wT64,
                                                         const double* __restrict__ sc,
                                                         const double* __restrict__ sh,
                                                         T* __restrict__ out,
                                                         const int* __restrict__ tbl) {
  if (tbl[768] == 0) return;
  __shared__ double Bs[2][32][68];
  int b = blockIdx.x, t0 = blockIdx.y * 64, tid = threadIdx.x;
  int wv = tid >> 6, l = tid & 63;
  int t_ma = tbl[l], t_ka = tbl[64 + l], t_kb = tbl[128 + l], t_nb = tbl[192 + l];
  int t_rd[4], t_cd[4];
#pragma unroll
  for (int v = 0; v < 4; ++v) { t_rd[v] = tbl[256 + l * 4 + v]; t_cd[v] = tbl[512 + l * 4 + v]; }
  int o0 = wv * 16;
  d4 acc[4];
#pragma unroll
  for (int c = 0; c < 4; ++c) acc[c] = (d4){0.0, 0.0, 0.0, 0.0};
  int r = tid >> 3, l8 = tid & 7;
  // prologue: stage chunk 0 values
  double bv[8];
  {
    int srow = b * K + r;
    const T* gp = in + (size_t)srow * TLEN + t0;
    double s_ = sc[srow], h_ = sh[srow];
#pragma unroll
    for (int q = 0; q < 4; ++q) {
      int t = 2 * l8 + 16 * q;
      bv[2 * q]     = fmax((double)gp[t] * s_ + h_, 0.0);
      bv[2 * q + 1] = fmax((double)gp[t + 1] * s_ + h_, 0.0);
    }
  }
  for (int kc = 0; kc < K / 32; ++kc) {
    int cur = kc & 1;
#pragma unroll
    for (int q = 0; q < 4; ++q) {
      double2 v = {bv[2 * q], bv[2 * q + 1]};
      *(double2*)&Bs[cur][r][2 * l8 + 16 * q] = v;
    }
    __syncthreads();
    // prefetch next chunk raw values
    double xr[8];
    double s_ = 0.0, h_ = 0.0;
    if (kc + 1 < K / 32) {
      int srow = b * K + (kc + 1) * 32 + r;
      const T* gp = in + (size_t)srow * TLEN + t0;
      s_ = sc[srow]; h_ = sh[srow];
#pragma unroll
      for (int q = 0; q < 4; ++q) {
        int t = 2 * l8 + 16 * q;
        xr[2 * q] = (double)gp[t];
        xr[2 * q + 1] = (double)gp[t + 1];
      }
    }
#pragma unroll
    for (int k4 = 0; k4 < 32; k4 += 4) {
      double aF = wT64[(size_t)(kc * 32 + k4 + t_ka) * 64 + o0 + t_ma];
#pragma unroll
      for (int c = 0; c < 4; ++c) {
        double bF = Bs[cur][k4 + t_kb][c * 16 + t_nb];
        acc[c] = __builtin_amdgcn_mfma_f64_16x16x4f64(aF, bF, acc[c], 0, 0, 0);
      }
    }
    if (kc + 1 < K / 32) {
#pragma unroll
      for (int j = 0; j < 8; ++j) bv[j] = fmax(xr[j] * s_ + h_, 0.0);
    }
  }
#pragma unroll
  for (int c = 0; c < 4; ++c)
#pragma unroll
    for (int v = 0; v < 4; ++v)
      out[((size_t)(b * 64 + o0 + t_rd[v])) * TLEN + t0 + c * 16 + t_cd[v]] = (T)acc[c][v];
}

// ---------------- 1x1 conv VALU twin (fused norm; runs only if probe failed) --------
template <int K, typename T>
__global__ __launch_bounds__(256, 4) void k_conv1x1_valu(const T* __restrict__ in,
                                                         const float* __restrict__ w,
                                                         const double* __restrict__ sc,
                                                         const double* __restrict__ sh,
                                                         T* __restrict__ out,
                                                         const int* __restrict__ tbl) {
  if (tbl[768] != 0) return;
  __shared__ float AsT[32][68];
  __shared__ double Bs[32][64];
  int b = blockIdx.x, t0 = blockIdx.y * 64, tid = threadIdx.x;
  double acc[4][4] = {};
  int to = (tid >> 4) * 4, l = tid & 15;
  for (int kc = 0; kc < K / 32; ++kc) {
    __syncthreads();
    {
      int idx = tid * 4;
#pragma unroll
      for (int rep = 0; rep < 2; ++rep) {
        int o = idx >> 5, ii = idx & 31;
        float4 v4 = *(const float4*)(w + (size_t)o * K + kc * 32 + ii);
        AsT[ii][o] = v4.x; AsT[ii + 1][o] = v4.y; AsT[ii + 2][o] = v4.z; AsT[ii + 3][o] = v4.w;
        idx += 1024;
      }
    }
    {
      int r = tid >> 3, l8 = tid & 7;
      int srow = b * K + kc * 32 + r;
      const T* gp = in + (size_t)srow * TLEN + t0;
      double s_ = sc[srow], h_ = sh[srow];
#pragma unroll
      for (int q = 0; q < 4; ++q) {
        int t = 2 * l8 + 16 * q;
        double2 v = {fmax((double)gp[t] * s_ + h_, 0.0),
                     fmax((double)gp[t + 1] * s_ + h_, 0.0)};
        *(double2*)&Bs[r][t] = v;
      }
    }
    __syncthreads();
#pragma unroll
    for (int kk = 0; kk < 32; ++kk) {
      float4 a4 = *(const float4*)&AsT[kk][to];
      double a0 = (double)a4.x, a1 = (double)a4.y, a2 = (double)a4.z, a3 = (double)a4.w;
      double bb[4];
#pragma unroll
      for (int j = 0; j < 2; ++j) {
        double2 p = *(const double2*)&Bs[kk][2 * l + 32 * j];
        bb[2 * j] = p.x; bb[2 * j + 1] = p.y;
      }
#pragma unroll
      for (int j = 0; j < 4; ++j) {
        acc[0][j] += a0 * bb[j];
        acc[1][j] += a1 * bb[j];
        acc[2][j] += a2 * bb[j];
        acc[3][j] += a3 * bb[j];
      }
    }
  }
#pragma unroll
  for (int q = 0; q < 4; ++q) {
    T* op = out + ((size_t)(b * 64 + to + q)) * TLEN + t0;
    op[2 * l]      = (T)acc[q][0];
    op[2 * l + 1]  = (T)acc[q][1];
    op[2 * l + 32] = (T)acc[q][2];
    op[2 * l + 33] = (T)acc[q][3];
  }
}

// ---------------- temporal conv via f64 MFMA: weights direct from global (L2) -------
template <typename T>
__global__ __launch_bounds__(512, 2) void k_tconv1_mfma(const T* __restrict__ h2,
                                                        const float* __restrict__ wT,
                                                        const double* __restrict__ sc,
                                                        const double* __restrict__ sh,
                                                        T* __restrict__ h3,
                                                        const int* __restrict__ tbl) {
  if (tbl[768] == 0) return;
  __shared__ __align__(16) double In[64][80];   // x: 0..77 <-> t = t0-7 .. t0+70
  int b = blockIdx.x, t0 = blockIdx.y * 64, tid = threadIdx.x;
  int wv = tid >> 6, l = tid & 63;
  int t_ma = tbl[l], t_ka = tbl[64 + l], t_kb = tbl[128 + l], t_nb = tbl[192 + l];
  int t_rd[4], t_cd[4];
#pragma unroll
  for (int v = 0; v < 4; ++v) { t_rd[v] = tbl[256 + l * 4 + v]; t_cd[v] = tbl[512 + l * 4 + v]; }
  int o0 = (wv >> 1) * 16, tq = (wv & 1) * 32;
  const float* wAp = wT + (size_t)t_ka * 64 + o0 + t_ma;   // + (k*64 + ic*8 + kg*4)*64
  for (int idx = tid; idx < 64 * 78; idx += 512) {
    int i = idx / 78, x = idx - i * 78;
    int tg = t0 - 7 + x;
    int row = b * 64 + i;
    double v = 0.0;
    if (tg >= 0 && tg < TLEN)
      v = fmax((double)h2[(size_t)row * TLEN + tg] * sc[row] + sh[row], 0.0);
    In[i][x] = v;
  }
  __syncthreads();
  d4 acc[2];
  acc[0] = (d4){0.0, 0.0, 0.0, 0.0};
  acc[1] = (d4){0.0, 0.0, 0.0, 0.0};
  for (int ic = 0; ic < 8; ++ic) {
#pragma unroll
    for (int k = 0; k < 15; ++k) {
#pragma unroll
      for (int kg = 0; kg < 2; ++kg) {
        double aF = (double)wAp[(size_t)(k * 64 + ic * 8 + kg * 4) * 64];
#pragma unroll
        for (int c = 0; c < 2; ++c) {
          double bF = In[ic * 8 + kg * 4 + t_kb][tq + c * 16 + t_nb + k];
          acc[c] = __builtin_amdgcn_mfma_f64_16x16x4f64(aF, bF, acc[c], 0, 0, 0);
        }
      }
    }
  }
#pragma unroll
  for (int c = 0; c < 2; ++c)
#pragma unroll
    for (int v = 0; v < 4; ++v)
      h3[((size_t)(b * 64 + o0 + t_rd[v])) * TLEN + t0 + tq + c * 16 + t_cd[v]] = (T)acc[c][v];
}

// ---------------- tconv1 VALU twin (fused IN2; runs only if probe failed) -----------
template <typename T>
__global__ __launch_bounds__(256) void k_tconv1_valu(const T* __restrict__ h2,
                                                     const float* __restrict__ wT,
                                                     const double* __restrict__ sc,
                                                     const double* __restrict__ sh,
                                                     T* __restrict__ h3,
                                                     const int* __restrict__ tbl) {
  if (tbl[768] != 0) return;
  __shared__ __align__(16) double In[64][80];
  __shared__ float Ws[8][15][64];
  int b = blockIdx.x, t0 = blockIdx.y * 64, tid = threadIdx.x;
  for (int idx = tid; idx < 64 * 78; idx += 256) {
    int i = idx / 78, x = idx - i * 78;
    int tg = t0 - 7 + x;
    int row = b * 64 + i;
    double v = 0.0;
    if (tg >= 0 && tg < TLEN)
      v = fmax((double)h2[(size_t)row * TLEN + tg] * sc[row] + sh[row], 0.0);
    In[i][x] = v;
  }
  double acc[4][4] = {};
  int og = (tid >> 4) * 4, tt2 = (tid & 15) * 4;
  for (int ic = 0; ic < 8; ++ic) {
    __syncthreads();
    for (int idx = tid; idx < 15 * 8 * 16; idx += 256) {
      int k = idx >> 7;
      int r = idx & 127;
      int ii = r >> 4, o4 = (r & 15) * 4;
      float4 v = *(const float4*)(wT + ((size_t)(k * 64 + ic * 8 + ii)) * 64 + o4);
      *(float4*)&Ws[ii][k][o4] = v;
    }
    __syncthreads();
#pragma unroll
    for (int ii = 0; ii < 8; ++ii) {
      int i = ic * 8 + ii;
      double r[18];
#pragma unroll
      for (int m = 0; m < 18; m += 2) {
        double2 p = *(const double2*)&In[i][tt2 + m];
        r[m] = p.x; r[m + 1] = p.y;
      }
#pragma unroll
      for (int k = 0; k < 15; ++k) {
        float4 w4 = *(const float4*)&Ws[ii][k][og];
        double w0 = (double)w4.x, w1 = (double)w4.y, w2 = (double)w4.z, w3 = (double)w4.w;
#pragma unroll
        for (int j = 0; j < 4; ++j) {
          double x = r[j + k];
          acc[0][j] += w0 * x;
          acc[1][j] += w1 * x;
          acc[2][j] += w2 * x;
          acc[3][j] += w3 * x;
        }
      }
    }
  }
#pragma unroll
  for (int q = 0; q < 4; ++q) {
    T* op = h3 + ((size_t)(b * 64 + og + q)) * TLEN + t0 + tt2;
#pragma unroll
    for (int j = 0; j < 4; ++j) op[j] = (T)acc[q][j];
  }
}

// ---------------- IN4 + relu + avgpool8 -> cbuf[row][tp], f64 -----------------------
template <typename T>
__global__ __launch_bounds__(256) void k_in4_pool(const T* __restrict__ h,
                                                  const float* __restrict__ gw,
                                                  const float* __restrict__ gb,
                                                  T* __restrict__ cbuf) {
  __shared__ double sm[4];
  int row = blockIdx.x, tid = threadIdx.x;
  int ch = row & 63;
  const T* base = h + (size_t)row * TLEN + tid * 8;
  double v[8];
#pragma unroll
  for (int j = 0; j < 8; ++j) v[j] = (double)base[j];
  double s = 0.0;
#pragma unroll
  for (int j = 0; j < 8; ++j) s += v[j];
  double mean = block_reduce_sum_d(s, sm) * (1.0 / 2048.0);
  double sq = 0.0;
#pragma unroll
  for (int j = 0; j < 8; ++j) { double d = v[j] - mean; sq += d * d; }
  double var = block_reduce_sum_d(sq, sm) * (1.0 / 2048.0);
  double scale = (double)gw[ch] / sqrt(var + 1e-5);
  double shift = (double)gb[ch] - mean * scale;
  double p = 0.0;
#pragma unroll
  for (int j = 0; j < 8; ++j) p += fmax(v[j] * scale + shift, 0.0);
  cbuf[(size_t)row * TP + tid] = (T)(p * 0.125);
}

// ---------------- GD-LIF scan + ONLINE softmax attention readout (single pass) ------
template <typename T>
__global__ __launch_bounds__(64) void k_scan(const T* __restrict__ cbuf,
                                             const T* __restrict__ curvp,
                                             const T* __restrict__ tangp,
                                             const float* __restrict__ alpha,
                                             const float* __restrict__ gamma,
                                             const float* __restrict__ betal,
                                             double* __restrict__ ofeat) {
  int id = blockIdx.x * 64 + threadIdx.x;  // b*64+c
  double a = (double)alpha[0], g = (double)gamma[0], bl = (double)betal[0];
  const T* cu_p = curvp + (size_t)id * TP;
  const T* ta_p = tangp + (size_t)id * TP;
  const T* cb_p = cbuf + (size_t)id * TP;
  double mmax = -1e300, ssum = 0.0, accs = 0.0, mem = 0.0;
  for (int tp = 0; tp < TP; ++tp) {
    double cu = (double)cu_p[tp];
    double ta = (double)ta_p[tp];
    double x = (double)cb_p[tp];
    double nm = fmax(mmax, cu);
    double r = exp(mmax - nm);
    double e = exp(cu - nm);
    ssum = ssum * r + e;
    accs = accs * r;
    mmax = nm;
    double vth = 1.0 + a * ta;
    double beta = 1.0 / (1.0 + exp(g * cu - bl));
    mem = beta * mem + x;
    if (mem - vth > 0.0) {
      accs += e;
      mem -= vth;
    }
  }
  ofeat[id] = accs / ssum;
}

// ---------------- final fc: (32,64) @ (4,64)^T + b, f64 -----------------------------
__global__ void k_fc(const double* __restrict__ ofeat, const float* __restrict__ fw,
                     const float* __restrict__ fb, float* __restrict__ out) {
  int tid = threadIdx.x;
  if (tid >= 128) return;
  int b = tid >> 2, j = tid & 3;
  double s = (double)fb[j];
#pragma unroll
  for (int c = 0; c < 64; ++c) s += ofeat[b * 64 + c] * (double)fw[j * 64 + c];
  out[b * 4 + j] = (float)s;
}

// ---------------- host-side templated launcher --------------------------------------
template <typename T>
static void run_all(void* const* d_in, float* out, char* wsb, hipStream_t stream) {
  const float* xb    = (const float*)d_in[0];
  const float* mu    = (const float*)d_in[1];
  const float* sigma = (const float*)d_in[2];
  const float* w1    = (const float*)d_in[3];
  const float* in1w  = (const float*)d_in[4];
  const float* in1b  = (const float*)d_in[5];
  const float* w2    = (const float*)d_in[6];
  const float* in2w  = (const float*)d_in[7];
  const float* in2b  = (const float*)d_in[8];
  const float* wt1   = (const float*)d_in[9];
  const float* in3w  = (const float*)d_in[10];
  const float* in3b  = (const float*)d_in[11];
  const float* w4    = (const float*)d_in[12];
  const float* in4w  = (const float*)d_in[13];
  const float* in4b  = (const float*)d_in[14];
  const float* alpha = (const float*)d_in[15];
  const float* gamma = (const float*)d_in[16];
  const float* betal = (const float*)d_in[17];
  const float* fcw   = (const float*)d_in[18];
  const float* fcb   = (const float*)d_in[19];

  size_t sT = sizeof(T);
  T* h1 = (T*)wsb;                                   // 8,388,608 elems (alias h3)
  T* h2 = (T*)(wsb + (size_t)8388608 * sT);          // 4,194,304 elems (alias h4)
  T* h3 = h1;
  T* h4 = h2;
  float* wT = (float*)(wsb + (size_t)12582912 * sT); // 61,440 f32
  char* p = wsb + (size_t)12582912 * sT + 245760;
  T* curvp = (T*)p;
  T* tangp = (T*)(p + (size_t)524288 * sT);
  T* cbuf  = (T*)(p + (size_t)2 * 524288 * sT);
  double* ofeat = (double*)(p + (size_t)3 * 524288 * sT);
  // probe tables + norm stats + f64 weight transposes live in cbuf region
  // (dead until k_in4_pool). Footprint: 16384 + 131072 + 786432 + 65536 + 32768
  // = 1,032,192 B < 524288*sizeof(T) for both T=double (4MB) and T=float (2MB).
  char* cb = (char*)cbuf;
  int* tbl = (int*)cb;                     // 769 ints
  double* sc1 = (double*)(cb + 16384);     // 4096
  double* sh1 = sc1 + 4096;                // 4096
  double* sc2 = sh1 + 4096;                // 2048
  double* sh2 = sc2 + 2048;                // 2048
  double* sc3 = sh2 + 2048;                // 2048
  double* sh3 = sc3 + 2048;                // 2048   (ends at 147,456)
  double* w1T = (double*)(cb + 147456);    // 98,304 f64
  double* w2T = w1T + 98304;               // 8,192 f64
  double* w4T = w2T + 8192;                // 4,096 f64

  k_repack_w<<<dim3(240), dim3(256), 0, stream>>>(wt1, wT);
  k_prep_w64<<<dim3(432), dim3(256), 0, stream>>>(w1, w2, w4, w1T, w2T, w4T);
  k_pool_ct<T><<<dim3(2048), dim3(256), 0, stream>>>(xb, curvp, tangp);
  k_probe_f64<<<dim3(1), dim3(64), 0, stream>>>(tbl);
  k_enc1_mfma<T><<<dim3(32, 32), dim3(256), 0, stream>>>(xb, w1T, mu, sigma, h1, tbl);
  k_enc1_valu<T><<<dim3(32, 32), dim3(256), 0, stream>>>(xb, w1, mu, sigma, h1, tbl);
  k_stats<T><<<dim3(4096), dim3(256), 0, stream>>>(h1, in1w, in1b, 127, sc1, sh1);
  k_conv1x1_mfma<128, T><<<dim3(32, 32), dim3(256), 0, stream>>>(h1, w2T, sc1, sh1, h2, tbl);
  k_conv1x1_valu<128, T><<<dim3(32, 32), dim3(256), 0, stream>>>(h1, w2, sc1, sh1, h2, tbl);
  k_stats<T><<<dim3(2048), dim3(256), 0, stream>>>(h2, in2w, in2b, 63, sc2, sh2);
  k_tconv1_mfma<T><<<dim3(32, 32), dim3(512), 0, stream>>>(h2, wT, sc2, sh2, h3, tbl);
  k_tconv1_valu<T><<<dim3(32, 32), dim3(256), 0, stream>>>(h2, wT, sc2, sh2, h3, tbl);
  k_stats<T><<<dim3(2048), dim3(256), 0, stream>>>(h3, in3w, in3b, 63, sc3, sh3);
  k_conv1x1_mfma<64, T><<<dim3(32, 32), dim3(256), 0, stream>>>(h3, w4T, sc3, sh3, h4, tbl);
  k_conv1x1_valu<64, T><<<dim3(32, 32), dim3(256), 0, stream>>>(h3, w4, sc3, sh3, h4, tbl);
  k_in4_pool<T><<<dim3(2048), dim3(256), 0, stream>>>(h4, in4w, in4b, cbuf);
  k_scan<T><<<dim3(32), dim3(64), 0, stream>>>(cbuf, curvp, tangp, alpha, gamma, betal, ofeat);
  k_fc<<<dim3(1), dim3(128), 0, stream>>>(ofeat, fcw, fcb, out);
}

extern "C" void kernel_launch(void* const* d_in, const int* in_sizes, int n_in,
                              void* d_out, int out_size, void* d_ws, size_t ws_size,
                              hipStream_t stream) {
  // f64-storage footprint: 12,582,912*8 + 245,760 + 3*524,288*8 + 16,384 = 113,508,352 B
  const size_t NEED64 = 113508352ull;
  if (ws_size >= NEED64)
    run_all<double>(d_in, (float*)d_out, (char*)d_ws, stream);
  else
    run_all<float>(d_in, (float*)d_out, (char*)d_ws, stream);
}

// Round 17
// 585.338 us; speedup vs baseline: 1.0397x; 1.0397x over previous
//
#include <hip/hip_runtime.h>
#include <math.h>

#define TLEN 2048
#define TP 256

typedef double d4 __attribute__((ext_vector_type(4)));

// ---------------- helpers ----------------
__device__ __forceinline__ double block_reduce_sum_d(double v, double* sm) {
#pragma unroll
  for (int off = 32; off > 0; off >>= 1) v += __shfl_down(v, off, 64);
  int lane = threadIdx.x & 63, wid = threadIdx.x >> 6;
  __syncthreads();
  if (lane == 0) sm[wid] = v;
  __syncthreads();
  double r = sm[0] + sm[1] + sm[2] + sm[3];
  __syncthreads();
  return r;
}

// ---------------- f64-MFMA layout probe (wave-parallel, proven round 8) -------------
// tbl: ma[64] ka[64] kb[64] nb[64] rd[64*4] cd[64*4] ok   (769 ints)
__global__ void k_probe_f64(int* __restrict__ tbl) {
  int l = threadIdx.x;  // single wave of 64
  __shared__ int kaS[64], kbS[64];
  __shared__ int cnt[256];
  int rdv[4] = {-1, -1, -1, -1}, cdv[4] = {-1, -1, -1, -1};
  int mav = -1, nbv = -1;
  int okr = 1;
  int nrow = 0, ncol = 0;
  kaS[l] = -1; kbS[l] = -1;
  __syncthreads();

  for (int j = 0; j < 64; ++j) {
    double a = (l == j) ? 1.0 : 0.0;
    d4 acc = {0.0, 0.0, 0.0, 0.0};
    acc = __builtin_amdgcn_mfma_f64_16x16x4f64(a, 1.0, acc, 0, 0, 0);
    int mylab = -1;
#pragma unroll
    for (int v = 0; v < 4; ++v) if (acc[v] != 0.0 && rdv[v] >= 0) mylab = rdv[v];
#pragma unroll
    for (int off = 32; off >= 1; off >>= 1) {
      int o = __shfl_xor(mylab, off);
      mylab = mylab > o ? mylab : o;
    }
    int label = (mylab < 0) ? nrow : mylab;
    if (mylab < 0) nrow++;
    if (label >= 16) okr = 0;
#pragma unroll
    for (int v = 0; v < 4; ++v) if (acc[v] != 0.0) rdv[v] = label;
    if (l == j) mav = label;
  }

  for (int j = 0; j < 64; ++j) {
    double bb = (l == j) ? 1.0 : 0.0;
    d4 acc = {0.0, 0.0, 0.0, 0.0};
    acc = __builtin_amdgcn_mfma_f64_16x16x4f64(1.0, bb, acc, 0, 0, 0);
    int mylab = -1;
#pragma unroll
    for (int v = 0; v < 4; ++v) if (acc[v] != 0.0 && cdv[v] >= 0) mylab = cdv[v];
#pragma unroll
    for (int off = 32; off >= 1; off >>= 1) {
      int o = __shfl_xor(mylab, off);
      mylab = mylab > o ? mylab : o;
    }
    int label = (mylab < 0) ? ncol : mylab;
    if (mylab < 0) ncol++;
    if (label >= 16) okr = 0;
#pragma unroll
    for (int v = 0; v < 4; ++v) if (acc[v] != 0.0) cdv[v] = label;
    if (l == j) nbv = label;
  }

  unsigned long long row0 = __ballot(mav == 0);
  if (__popcll(row0) != 4) okr = 0;
  for (int i = 0; i < 4; ++i) {
    int rep = -1, idx = -1;
    for (int t = 0; t < 64; ++t)
      if ((row0 >> t) & 1ull) { if (++idx == i) { rep = t; break; } }
    double a = (l == rep) ? 1.0 : 0.0;
    double bb = (double)(l + 1);
    d4 acc = {0.0, 0.0, 0.0, 0.0};
    acc = __builtin_amdgcn_mfma_f64_16x16x4f64(a, bb, acc, 0, 0, 0);
#pragma unroll
    for (int v = 0; v < 4; ++v)
      if (rdv[v] == 0) {
        int jp = (int)(acc[v] + 0.5) - 1;
        if (jp >= 0 && jp < 64) kbS[jp] = i; else okr = 0;
      }
  }
  __syncthreads();
  int kbv = kbS[l];

  for (int i = 0; i < 4; ++i) {
    unsigned long long bm = __ballot(kbv == i);
    int rep = -1;
    if (bm != 0ull) { rep = 0; while (!((bm >> rep) & 1ull)) ++rep; }
    else okr = 0;
    int nc = (rep >= 0) ? __shfl(nbv, rep) : -2;
    double bb = (l == rep) ? 1.0 : 0.0;
    double aa = (double)(l + 1);
    d4 acc = {0.0, 0.0, 0.0, 0.0};
    acc = __builtin_amdgcn_mfma_f64_16x16x4f64(aa, bb, acc, 0, 0, 0);
#pragma unroll
    for (int v = 0; v < 4; ++v)
      if (cdv[v] == nc) {
        int jp = (int)(acc[v] + 0.5) - 1;
        if (jp >= 0 && jp < 64) kaS[jp] = i; else okr = 0;
      }
  }
  __syncthreads();
  int kav = kaS[l];

  if (nrow != 16 || ncol != 16) okr = 0;
  if (mav < 0 || mav > 15 || nbv < 0 || nbv > 15 ||
      kav < 0 || kav > 3 || kbv < 0 || kbv > 3) okr = 0;
#pragma unroll
  for (int v = 0; v < 4; ++v)
    if (rdv[v] < 0 || rdv[v] > 15 || cdv[v] < 0 || cdv[v] > 15) okr = 0;
  cnt[l] = 0; cnt[64 + l] = 0; cnt[128 + l] = 0; cnt[192 + l] = 0;
  __syncthreads();
  if (mav >= 0 && mav < 16 && kav >= 0 && kav < 4) atomicAdd(&cnt[mav * 4 + kav], 1);
  if (kbv >= 0 && kbv < 4 && nbv >= 0 && nbv < 16) atomicAdd(&cnt[64 + kbv * 16 + nbv], 1);
  __syncthreads();
  if (cnt[l] != 1 || cnt[64 + l] != 1) okr = 0;
  __syncthreads();
  cnt[l] = 0; cnt[64 + l] = 0; cnt[128 + l] = 0; cnt[192 + l] = 0;
  __syncthreads();
#pragma unroll
  for (int v = 0; v < 4; ++v)
    if (rdv[v] >= 0 && rdv[v] < 16 && cdv[v] >= 0 && cdv[v] < 16)
      atomicAdd(&cnt[rdv[v] * 16 + cdv[v]], 1);
  __syncthreads();
#pragma unroll
  for (int v = 0; v < 4; ++v) if (cnt[l * 4 + v] != 1) okr = 0;
  if (mav == 0) {
    int rank = (int)__popcll(row0 & ((1ull << l) - 1ull));
    if (kav != rank) okr = 0;
  }
  unsigned long long good = __ballot(okr != 0);
  tbl[l] = mav; tbl[64 + l] = kav; tbl[128 + l] = kbv; tbl[192 + l] = nbv;
#pragma unroll
  for (int v = 0; v < 4; ++v) {
    tbl[256 + l * 4 + v] = rdv[v];
    tbl[512 + l * 4 + v] = cdv[v];
  }
  if (l == 0) tbl[768] = (good == 0xFFFFFFFFFFFFFFFFull) ? 1 : 0;
}

// ---------------- repack tconv1 weights: w[o][i][k] -> wT[k][i][o] (f32, exact) ------
__global__ void k_repack_w(const float* __restrict__ w, float* __restrict__ wT) {
  int idx = blockIdx.x * 256 + threadIdx.x;
  if (idx >= 64 * 64 * 15) return;
  int o = idx & 63, i = (idx >> 6) & 63, k = idx >> 12;
  wT[idx] = w[(o * 64 + i) * 15 + k];
}

// ---------------- pooled streams -> row-major [row][tp] ----------------
template <typename T>
__global__ __launch_bounds__(256) void k_pool_ct(const float* __restrict__ xb,
                                                 T* __restrict__ curvp,
                                                 T* __restrict__ tangp) {
  int row = blockIdx.x;  // b*64+c
  int b = row >> 6, c = row & 63;
  int tid = threadIdx.x;
  const float* s1 = xb + ((size_t)((b * 3 + 1) * 64 + c)) * TLEN + tid * 8;
  const float* s2 = xb + ((size_t)((b * 3 + 2) * 64 + c)) * TLEN + tid * 8;
  double p1 = 0.0, p2 = 0.0;
#pragma unroll
  for (int j = 0; j < 8; ++j) { p1 += (double)s1[j]; p2 += (double)s2[j]; }
  curvp[(size_t)row * TP + tid] = (T)(p1 * 0.125);
  tangp[(size_t)row * TP + tid] = (T)(p2 * 0.125);
}

// ---------------- instance-norm stats only: per-row scale/shift ---------------------
template <typename T>
__global__ __launch_bounds__(256) void k_stats(const T* __restrict__ h,
                                               const float* __restrict__ gw,
                                               const float* __restrict__ gb,
                                               int chmask,
                                               double* __restrict__ sc,
                                               double* __restrict__ sh) {
  __shared__ double sm[4];
  int row = blockIdx.x, tid = threadIdx.x;
  int ch = row & chmask;
  const T* base = h + (size_t)row * TLEN + tid * 8;
  double v[8];
#pragma unroll
  for (int j = 0; j < 8; ++j) v[j] = (double)base[j];
  double s = 0.0;
#pragma unroll
  for (int j = 0; j < 8; ++j) s += v[j];
  double mean = block_reduce_sum_d(s, sm) * (1.0 / 2048.0);
  double sq = 0.0;
#pragma unroll
  for (int j = 0; j < 8; ++j) { double d = v[j] - mean; sq += d * d; }
  double var = block_reduce_sum_d(sq, sm) * (1.0 / 2048.0);
  double scale = (double)gw[ch] / sqrt(var + 1e-5);
  double shift = (double)gb[ch] - mean * scale;
  if (tid == 0) { sc[row] = scale; sh[row] = shift; }
}

// ---------------- enc+conv1 via f64 MFMA: 128 o x 128 t, 8 waves, PIPELINED ---------
// Round-15 configuration (best measured: 262 us, VGPR 64, no spill).
template <typename T>
__global__ __launch_bounds__(512, 4) void k_enc1_mfma(const float* __restrict__ xb,
                                                      const float* __restrict__ w,
                                                      const float* __restrict__ mu,
                                                      const float* __restrict__ sigma,
                                                      T* __restrict__ h1,
                                                      const int* __restrict__ tbl) {
  __shared__ float AsT[32][132];    // [local i][o 0..127]
  __shared__ double Bs[32][132];    // [local i][t 0..127]
  int b = blockIdx.x, t0 = blockIdx.y * 128, tid = threadIdx.x;
  int wv = tid >> 6, l = tid & 63;
  int o0 = (wv >> 1) * 32, tb = (wv & 1) * 64;
  int t_ma = tbl[l], t_ka = tbl[64 + l], t_kb = tbl[128 + l], t_nb = tbl[192 + l];
  int t_rd[4], t_cd[4];
#pragma unroll
  for (int v = 0; v < 4; ++v) { t_rd[v] = tbl[256 + l * 4 + v]; t_cd[v] = tbl[512 + l * 4 + v]; }
  double smu[4], sinv[4];
#pragma unroll
  for (int g = 0; g < 4; ++g) {
    smu[g] = (double)mu[g];
    double s = (double)sigma[g];
    sinv[g] = 1.0 / (2.0 * s * s + 1e-6);
  }
  d4 acc[2][4];
#pragma unroll
  for (int r = 0; r < 2; ++r)
#pragma unroll
    for (int c = 0; c < 4; ++c) acc[r][c] = (d4){0.0, 0.0, 0.0, 0.0};

  int aO1 = (tid * 4) >> 5, aI1 = (tid * 4) & 31;
  int aO2 = (tid * 4 + 2048) >> 5, aI2 = (tid * 4 + 2048) & 31;
  int sc_ = tid >> 6, sl2 = tid & 63;
  int st = 2 * sl2;

  float4 a1r = *(const float4*)(w + (size_t)aO1 * 768 + aI1);
  float4 a2r = *(const float4*)(w + (size_t)aO2 * 768 + aI2);
  double e[8];
  {
    float2 x2 = *(const float2*)(xb + ((size_t)((b * 3 + 0) * 64 + 0 + sc_)) * TLEN + t0 + st);
    double xv0 = (double)x2.x, xv1 = (double)x2.y;
#pragma unroll
    for (int g = 0; g < 4; ++g) {
      double d0 = xv0 - smu[g], d1 = xv1 - smu[g];
      e[2 * g] = exp(-d0 * d0 * sinv[g]);
      e[2 * g + 1] = exp(-d1 * d1 * sinv[g]);
    }
  }

  for (int kc = 0; kc < 24; ++kc) {
    __syncthreads();
    AsT[aI1][aO1] = a1r.x; AsT[aI1 + 1][aO1] = a1r.y;
    AsT[aI1 + 2][aO1] = a1r.z; AsT[aI1 + 3][aO1] = a1r.w;
    AsT[aI2][aO2] = a2r.x; AsT[aI2 + 1][aO2] = a2r.y;
    AsT[aI2 + 2][aO2] = a2r.z; AsT[aI2 + 3][aO2] = a2r.w;
#pragma unroll
    for (int g = 0; g < 4; ++g) {
      double2 ev = {e[2 * g], e[2 * g + 1]};
      *(double2*)&Bs[sc_ * 4 + g][st] = ev;
    }
    __syncthreads();
#pragma unroll
    for (int k4 = 0; k4 < 32; k4 += 4) {
      double aF0 = (double)AsT[k4 + t_ka][o0 + t_ma];
      double aF1 = (double)AsT[k4 + t_ka][o0 + 16 + t_ma];
      double bF[4];
#pragma unroll
      for (int c = 0; c < 4; ++c) bF[c] = Bs[k4 + t_kb][tb + c * 16 + t_nb];
#pragma unroll
      for (int c = 0; c < 4; ++c) {
        acc[0][c] = __builtin_amdgcn_mfma_f64_16x16x4f64(aF0, bF[c], acc[0][c], 0, 0, 0);
        acc[1][c] = __builtin_amdgcn_mfma_f64_16x16x4f64(aF1, bF[c], acc[1][c], 0, 0, 0);
      }
    }
    if (kc < 23) {
      int i0n = (kc + 1) * 32;
      a1r = *(const float4*)(w + (size_t)aO1 * 768 + i0n + aI1);
      a2r = *(const float4*)(w + (size_t)aO2 * 768 + i0n + aI2);
      int f = i0n >> 8;
      int cb = (i0n >> 2) & 63;
      float2 x2 = *(const float2*)(xb + ((size_t)((b * 3 + f) * 64 + cb + sc_)) * TLEN + t0 + st);
      double xv0 = (double)x2.x, xv1 = (double)x2.y;
#pragma unroll
      for (int g = 0; g < 4; ++g) {
        double d0 = xv0 - smu[g], d1 = xv1 - smu[g];
        e[2 * g] = exp(-d0 * d0 * sinv[g]);
        e[2 * g + 1] = exp(-d1 * d1 * sinv[g]);
      }
    }
  }
#pragma unroll
  for (int r = 0; r < 2; ++r)
#pragma unroll
    for (int c = 0; c < 4; ++c)
#pragma unroll
      for (int v = 0; v < 4; ++v) {
        int o = o0 + r * 16 + t_rd[v];
        h1[((size_t)(b * 128 + o)) * TLEN + t0 + tb + c * 16 + t_cd[v]] = (T)acc[r][c][v];
      }
}

// ---------------- 1x1 conv via f64 MFMA, fused input-instnorm+relu (round 15) -------
template <int K, typename T>
__global__ __launch_bounds__(256, 4) void k_conv1x1_mfma(const T* __restrict__ in,
                                                         const float* __restrict__ w,
                                                         const double* __restrict__ sc,
                                                         const double* __restrict__ sh,
                                                         T* __restrict__ out,
                                                         const int* __restrict__ tbl) {
  __shared__ float AsT[32][68];     // [local i][o]
  __shared__ double Bs[32][68];
  int b = blockIdx.x, t0 = blockIdx.y * 64, tid = threadIdx.x;
  int wv = tid >> 6, l = tid & 63;
  int t_ma = tbl[l], t_ka = tbl[64 + l], t_kb = tbl[128 + l], t_nb = tbl[192 + l];
  int t_rd[4], t_cd[4];
#pragma unroll
  for (int v = 0; v < 4; ++v) { t_rd[v] = tbl[256 + l * 4 + v]; t_cd[v] = tbl[512 + l * 4 + v]; }
  int o0 = wv * 16;
  d4 acc[4];
#pragma unroll
  for (int c = 0; c < 4; ++c) acc[c] = (d4){0.0, 0.0, 0.0, 0.0};
  for (int kc = 0; kc < K / 32; ++kc) {
    __syncthreads();
    {
      int idx = tid * 4;
#pragma unroll
      for (int rep = 0; rep < 2; ++rep) {
        int o = idx >> 5, ii = idx & 31;
        float4 v4 = *(const float4*)(w + (size_t)o * K + kc * 32 + ii);
        AsT[ii][o] = v4.x; AsT[ii + 1][o] = v4.y; AsT[ii + 2][o] = v4.z; AsT[ii + 3][o] = v4.w;
        idx += 1024;
      }
    }
    {
      int r = tid >> 3, l8 = tid & 7;
      int srow = b * K + kc * 32 + r;
      const T* gp = in + (size_t)srow * TLEN + t0;
      double s_ = sc[srow], h_ = sh[srow];
#pragma unroll
      for (int q = 0; q < 4; ++q) {
        int t = 2 * l8 + 16 * q;
        double2 v = {fmax((double)gp[t] * s_ + h_, 0.0),
                     fmax((double)gp[t + 1] * s_ + h_, 0.0)};
        *(double2*)&Bs[r][t] = v;
      }
    }
    __syncthreads();
#pragma unroll
    for (int k4 = 0; k4 < 32; k4 += 4) {
      double aF = (double)AsT[k4 + t_ka][o0 + t_ma];
#pragma unroll
      for (int c = 0; c < 4; ++c) {
        double bF = Bs[k4 + t_kb][c * 16 + t_nb];
        acc[c] = __builtin_amdgcn_mfma_f64_16x16x4f64(aF, bF, acc[c], 0, 0, 0);
      }
    }
  }
#pragma unroll
  for (int c = 0; c < 4; ++c)
#pragma unroll
    for (int v = 0; v < 4; ++v)
      out[((size_t)(b * 64 + o0 + t_rd[v])) * TLEN + t0 + c * 16 + t_cd[v]] = (T)acc[c][v];
}

// ---------------- temporal conv via f64 MFMA: weights direct from global (L2) -------
template <typename T>
__global__ __launch_bounds__(512, 2) void k_tconv1_mfma(const T* __restrict__ h2,
                                                        const float* __restrict__ wT,
                                                        const double* __restrict__ sc,
                                                        const double* __restrict__ sh,
                                                        T* __restrict__ h3,
                                                        const int* __restrict__ tbl) {
  __shared__ __align__(16) double In[64][80];   // x: 0..77 <-> t = t0-7 .. t0+70
  int b = blockIdx.x, t0 = blockIdx.y * 64, tid = threadIdx.x;
  int wv = tid >> 6, l = tid & 63;
  int t_ma = tbl[l], t_ka = tbl[64 + l], t_kb = tbl[128 + l], t_nb = tbl[192 + l];
  int t_rd[4], t_cd[4];
#pragma unroll
  for (int v = 0; v < 4; ++v) { t_rd[v] = tbl[256 + l * 4 + v]; t_cd[v] = tbl[512 + l * 4 + v]; }
  int o0 = (wv >> 1) * 16, tq = (wv & 1) * 32;
  const float* wAp = wT + (size_t)t_ka * 64 + o0 + t_ma;   // + (k*64 + ic*8 + kg*4)*64
  for (int idx = tid; idx < 64 * 78; idx += 512) {
    int i = idx / 78, x = idx - i * 78;
    int tg = t0 - 7 + x;
    int row = b * 64 + i;
    double v = 0.0;
    if (tg >= 0 && tg < TLEN)
      v = fmax((double)h2[(size_t)row * TLEN + tg] * sc[row] + sh[row], 0.0);
    In[i][x] = v;
  }
  __syncthreads();
  d4 acc[2];
  acc[0] = (d4){0.0, 0.0, 0.0, 0.0};
  acc[1] = (d4){0.0, 0.0, 0.0, 0.0};
  for (int ic = 0; ic < 8; ++ic) {
#pragma unroll
    for (int k = 0; k < 15; ++k) {
#pragma unroll
      for (int kg = 0; kg < 2; ++kg) {
        double aF = (double)wAp[(size_t)(k * 64 + ic * 8 + kg * 4) * 64];
#pragma unroll
        for (int c = 0; c < 2; ++c) {
          double bF = In[ic * 8 + kg * 4 + t_kb][tq + c * 16 + t_nb + k];
          acc[c] = __builtin_amdgcn_mfma_f64_16x16x4f64(aF, bF, acc[c], 0, 0, 0);
        }
      }
    }
  }
#pragma unroll
  for (int c = 0; c < 2; ++c)
#pragma unroll
    for (int v = 0; v < 4; ++v)
      h3[((size_t)(b * 64 + o0 + t_rd[v])) * TLEN + t0 + tq + c * 16 + t_cd[v]] = (T)acc[c][v];
}

// ---------------- IN4 + relu + avgpool8 -> cbuf[row][tp], f64 -----------------------
template <typename T>
__global__ __launch_bounds__(256) void k_in4_pool(const T* __restrict__ h,
                                                  const float* __restrict__ gw,
                                                  const float* __restrict__ gb,
                                                  T* __restrict__ cbuf) {
  __shared__ double sm[4];
  int row = blockIdx.x, tid = threadIdx.x;
  int ch = row & 63;
  const T* base = h + (size_t)row * TLEN + tid * 8;
  double v[8];
#pragma unroll
  for (int j = 0; j < 8; ++j) v[j] = (double)base[j];
  double s = 0.0;
#pragma unroll
  for (int j = 0; j < 8; ++j) s += v[j];
  double mean = block_reduce_sum_d(s, sm) * (1.0 / 2048.0);
  double sq = 0.0;
#pragma unroll
  for (int j = 0; j < 8; ++j) { double d = v[j] - mean; sq += d * d; }
  double var = block_reduce_sum_d(sq, sm) * (1.0 / 2048.0);
  double scale = (double)gw[ch] / sqrt(var + 1e-5);
  double shift = (double)gb[ch] - mean * scale;
  double p = 0.0;
#pragma unroll
  for (int j = 0; j < 8; ++j) p += fmax(v[j] * scale + shift, 0.0);
  cbuf[(size_t)row * TP + tid] = (T)(p * 0.125);
}

// ---------------- GD-LIF scan + ONLINE softmax attention readout (single pass) ------
template <typename T>
__global__ __launch_bounds__(64) void k_scan(const T* __restrict__ cbuf,
                                             const T* __restrict__ curvp,
                                             const T* __restrict__ tangp,
                                             const float* __restrict__ alpha,
                                             const float* __restrict__ gamma,
                                             const float* __restrict__ betal,
                                             double* __restrict__ ofeat) {
  int id = blockIdx.x * 64 + threadIdx.x;  // b*64+c
  double a = (double)alpha[0], g = (double)gamma[0], bl = (double)betal[0];
  const T* cu_p = curvp + (size_t)id * TP;
  const T* ta_p = tangp + (size_t)id * TP;
  const T* cb_p = cbuf + (size_t)id * TP;
  double mmax = -1e300, ssum = 0.0, accs = 0.0, mem = 0.0;
  for (int tp = 0; tp < TP; ++tp) {
    double cu = (double)cu_p[tp];
    double ta = (double)ta_p[tp];
    double x = (double)cb_p[tp];
    double nm = fmax(mmax, cu);
    double r = exp(mmax - nm);
    double e = exp(cu - nm);
    ssum = ssum * r + e;
    accs = accs * r;
    mmax = nm;
    double vth = 1.0 + a * ta;
    double beta = 1.0 / (1.0 + exp(g * cu - bl));
    mem = beta * mem + x;
    if (mem - vth > 0.0) {
      accs += e;
      mem -= vth;
    }
  }
  ofeat[id] = accs / ssum;
}

// ---------------- final fc: (32,64) @ (4,64)^T + b, f64 -----------------------------
__global__ void k_fc(const double* __restrict__ ofeat, const float* __restrict__ fw,
                     const float* __restrict__ fb, float* __restrict__ out) {
  int tid = threadIdx.x;
  if (tid >= 128) return;
  int b = tid >> 2, j = tid & 3;
  double s = (double)fb[j];
#pragma unroll
  for (int c = 0; c < 64; ++c) s += ofeat[b * 64 + c] * (double)fw[j * 64 + c];
  out[b * 4 + j] = (float)s;
}

// ---------------- host-side templated launcher --------------------------------------
template <typename T>
static void run_all(void* const* d_in, float* out, char* wsb, hipStream_t stream) {
  const float* xb    = (const float*)d_in[0];
  const float* mu    = (const float*)d_in[1];
  const float* sigma = (const float*)d_in[2];
  const float* w1    = (const float*)d_in[3];
  const float* in1w  = (const float*)d_in[4];
  const float* in1b  = (const float*)d_in[5];
  const float* w2    = (const float*)d_in[6];
  const float* in2w  = (const float*)d_in[7];
  const float* in2b  = (const float*)d_in[8];
  const float* wt1   = (const float*)d_in[9];
  const float* in3w  = (const float*)d_in[10];
  const float* in3b  = (const float*)d_in[11];
  const float* w4    = (const float*)d_in[12];
  const float* in4w  = (const float*)d_in[13];
  const float* in4b  = (const float*)d_in[14];
  const float* alpha = (const float*)d_in[15];
  const float* gamma = (const float*)d_in[16];
  const float* betal = (const float*)d_in[17];
  const float* fcw   = (const float*)d_in[18];
  const float* fcb   = (const float*)d_in[19];

  size_t sT = sizeof(T);
  T* h1 = (T*)wsb;                                   // 8,388,608 elems (alias h3)
  T* h2 = (T*)(wsb + (size_t)8388608 * sT);          // 4,194,304 elems (alias h4)
  T* h3 = h1;
  T* h4 = h2;
  float* wT = (float*)(wsb + (size_t)12582912 * sT); // 61,440 f32
  char* p = wsb + (size_t)12582912 * sT + 245760;
  T* curvp = (T*)p;
  T* tangp = (T*)(p + (size_t)524288 * sT);
  T* cbuf  = (T*)(p + (size_t)2 * 524288 * sT);
  double* ofeat = (double*)(p + (size_t)3 * 524288 * sT);
  // probe tables + norm stats live in the cbuf region (dead until k_in4_pool)
  char* cb = (char*)cbuf;
  int* tbl = (int*)cb;                     // 769 ints
  double* sc1 = (double*)(cb + 16384);     // 4096
  double* sh1 = sc1 + 4096;                // 4096
  double* sc2 = sh1 + 4096;                // 2048
  double* sh2 = sc2 + 2048;                // 2048
  double* sc3 = sh2 + 2048;                // 2048
  double* sh3 = sc3 + 2048;                // 2048  (ends at 147,456 B < cbuf size)

  k_repack_w<<<dim3(240), dim3(256), 0, stream>>>(wt1, wT);
  k_pool_ct<T><<<dim3(2048), dim3(256), 0, stream>>>(xb, curvp, tangp);
  k_probe_f64<<<dim3(1), dim3(64), 0, stream>>>(tbl);
  k_enc1_mfma<T><<<dim3(32, 16), dim3(512), 0, stream>>>(xb, w1, mu, sigma, h1, tbl);
  k_stats<T><<<dim3(4096), dim3(256), 0, stream>>>(h1, in1w, in1b, 127, sc1, sh1);
  k_conv1x1_mfma<128, T><<<dim3(32, 32), dim3(256), 0, stream>>>(h1, w2, sc1, sh1, h2, tbl);
  k_stats<T><<<dim3(2048), dim3(256), 0, stream>>>(h2, in2w, in2b, 63, sc2, sh2);
  k_tconv1_mfma<T><<<dim3(32, 32), dim3(512), 0, stream>>>(h2, wT, sc2, sh2, h3, tbl);
  k_stats<T><<<dim3(2048), dim3(256), 0, stream>>>(h3, in3w, in3b, 63, sc3, sh3);
  k_conv1x1_mfma<64, T><<<dim3(32, 32), dim3(256), 0, stream>>>(h3, w4, sc3, sh3, h4, tbl);
  k_in4_pool<T><<<dim3(2048), dim3(256), 0, stream>>>(h4, in4w, in4b, cbuf);
  k_scan<T><<<dim3(32), dim3(64), 0, stream>>>(cbuf, curvp, tangp, alpha, gamma, betal, ofeat);
  k_fc<<<dim3(1), dim3(128), 0, stream>>>(ofeat, fcw, fcb, out);
}

extern "C" void kernel_launch(void* const* d_in, const int* in_sizes, int n_in,
                              void* d_out, int out_size, void* d_ws, size_t ws_size,
                              hipStream_t stream) {
  // f64-storage footprint: 12,582,912*8 + 245,760 + 3*524,288*8 + 16,384 = 113,508,352 B
  const size_t NEED64 = 113508352ull;
  if (ws_size >= NEED64)
    run_all<double>(d_in, (float*)d_out, (char*)d_ws, stream);
  else
    run_all<float>(d_in, (float*)d_out, (char*)d_ws, stream);
}